// Round 10
// baseline (3965.234 us; speedup 1.0000x reference)
//
#include <hip/hip_runtime.h>
#include <math.h>

#define HDIM 1024
#define BDIM 64
#define TDIM 512
#define KIN  128
#define NBLK 256
#define NTHR 512            // 8 waves
#define FRAME (HDIM * BDIM) // halfs per ring frame

typedef _Float16 f16;
typedef __attribute__((ext_vector_type(2))) _Float16 f16x2;
typedef __attribute__((ext_vector_type(8))) _Float16 f16x8;
typedef __attribute__((ext_vector_type(4))) float f32x4;

#define MFMA16(a, b, c) __builtin_amdgcn_mfma_f32_16x16x32_f16((a), (b), (c), 0, 0, 0)

__device__ __forceinline__ float sigm(float x) { return 1.0f / (1.0f + expf(-x)); }

// ---------------------------------------------------------------------------
// Octet ring layout (halfs): idx(k, m) = (k>>3)*512 + m*8 + (k&7).
// A-frag load = one dwordx4/lane; h-store = one dwordx2 wave-store per block.
// All ring I/O sc0sc1 (L3-coherent, fence-free).
// ---------------------------------------------------------------------------
__device__ __forceinline__ f16x8 ld_cg(const f16* p) {
    f16x8 r;
    asm volatile("global_load_dwordx4 %0, %1, off sc0 sc1"
                 : "=v"(r) : "v"(p) : "memory");
    return r;
}
#define VM_WAIT16(a0,a1,a2,a3,a4,a5,a6,a7,b0,b1,b2,b3,b4,b5,b6,b7)       \
    asm volatile("s_waitcnt vmcnt(0)"                                    \
                 : "+v"(a0), "+v"(a1), "+v"(a2), "+v"(a3),               \
                   "+v"(a4), "+v"(a5), "+v"(a6), "+v"(a7),               \
                   "+v"(b0), "+v"(b1), "+v"(b2), "+v"(b3),               \
                   "+v"(b4), "+v"(b5), "+v"(b6), "+v"(b7))

__device__ __forceinline__ void st_cg8(f16* p, uint2 v) {
    asm volatile("global_store_dwordx2 %0, %1, off sc0 sc1"
                 :: "v"(p), "v"(v) : "memory");
}
#define VM_DRAIN() asm volatile("s_waitcnt vmcnt(0)" ::: "memory")

// ---------------------------------------------------------------------------
// Flat-8 fence-free barrier: monotonic counters on 8 parallel 128B lines;
// wait = poll sum >= target. 2 arrivals per block per step (h1-wave, h2-wave).
// ---------------------------------------------------------------------------
__device__ __forceinline__ void bar_add(unsigned* base, int slot) {
    __hip_atomic_fetch_add(base + slot * 32, 1u, __ATOMIC_RELAXED,
                           __HIP_MEMORY_SCOPE_AGENT);
}
__device__ __forceinline__ void bar_wait(unsigned* base, unsigned target) {
    for (;;) {
        unsigned sum = 0;
        #pragma unroll
        for (int i = 0; i < 8; ++i)
            sum += __hip_atomic_load(base + i * 32, __ATOMIC_RELAXED,
                                     __HIP_MEMORY_SCOPE_AGENT);
        if (sum >= target) break;
        __builtin_amdgcn_s_sleep(1);
    }
}

// ---------------------------------------------------------------------------
__global__ void cvt_w(const float* __restrict__ src, f16* __restrict__ dst, int n2) {
    int i = blockIdx.x * blockDim.x + threadIdx.x;
    if (i < n2) {
        float2 a = ((const float2*)src)[i];
        f16x2 o = {(f16)a.x, (f16)a.y};
        ((f16x2*)dst)[i] = o;
    }
}

// x[b][t][k] fp32 -> xP[t][b][k] fp16
__global__ void cvt_x(const float* __restrict__ x, f16* __restrict__ xP) {
    int P = blockIdx.x * blockDim.x + threadIdx.x;    // pair index
    if (P >= TDIM * BDIM * (KIN / 2)) return;
    int kp = P & 63;
    int b  = (P >> 6) & 63;
    int t  = P >> 12;
    float2 v = ((const float2*)x)[((size_t)b * TDIM + t) * (KIN / 2) + kp];
    f16x2 o = {(f16)v.x, (f16)v.y};
    ((f16x2*)xP)[((size_t)t * BDIM + b) * (KIN / 2) + kp] = o;
}

// ---------------------------------------------------------------------------
// Fused 2-layer LSTM, merged single-reduction step.
// 256 blocks x 8 waves. Block owns 4 cols; wave K-slice = 128 (4 ksteps).
// Per step: one barrier wait -> A1 (h1^{s-1}) + A2 (h2^{s-2}) loads -> all
// three GEMV parts (Whh0*A1, Wih1*A1, Whh1*A2) -> ONE LDS reduce round
// (red1+red2, write w<4 / fold w>=4) -> parallel owners (w0-3: layer1+c1,
// w4-7: layer2+c2) -> LDS-staged coalesced h-stores (w0: h1, w1: h2) ->
// drain -> 2 arrivals. h published end-of-step; consumed top of next step.
// ---------------------------------------------------------------------------
__global__ void __launch_bounds__(NTHR, 2) lstm_fused(
    const f16* __restrict__ xP,
    const f16* __restrict__ Wc0, const f16* __restrict__ Wh0,
    const float* __restrict__ bih0, const float* __restrict__ bhh0,
    const f16* __restrict__ Wc1, const f16* __restrict__ Wh1,
    const float* __restrict__ bih1, const float* __restrict__ bhh1,
    f16* ring1, f16* ring2, unsigned* bar) {

    // red: 32 slot-groups x 324 words (~41.6 KB): groups 0..15 = layer1
    // (p*4+mt), groups 16..31 = layer2.
    __shared__ float red[32 * 324 + 16];
    __shared__ __align__(16) f16 hbuf1[BDIM * 4];
    __shared__ __align__(16) f16 hbuf2[BDIM * 4];

    const int tid  = threadIdx.x;
    const int lane = tid & 63;
    const int w    = __builtin_amdgcn_readfirstlane(tid >> 6);   // 0..7
    const int bid  = (int)blockIdx.x;
    const int iu4  = __builtin_amdgcn_readfirstlane(bid * 4);
    const int slot = bid & 7;

    const int n    = lane & 15;
    const int quad = lane >> 4;
    const int am   = lane & 15;
    const int wrow = iu4 + (n >> 2) + (n & 3) * HDIM;

    const int oct4 = iu4 >> 3;        // block's octet in ring layout
    const int coff = iu4 & 7;         // 0 or 4

    // ---- stationary weight fragments: K-slice 128 = 4 ksteps ----
    f16x8 B1h[4], B2i[4], B2h[4];
    f16x8 B1x;                        // w<4 only
    #pragma unroll
    for (int j = 0; j < 4; ++j) {
        const int ks = w * 128 + j * 32 + quad * 8;
        B1h[j] = *(const f16x8*)(Wh0 + (size_t)wrow * HDIM + ks);
        B2i[j] = *(const f16x8*)(Wc1 + (size_t)wrow * HDIM + ks);
        B2h[j] = *(const f16x8*)(Wh1 + (size_t)wrow * HDIM + ks);
    }
    if (w < 4)
        B1x = *(const f16x8*)(Wc0 + (size_t)wrow * KIN + w * 32 + quad * 8);

    // ---- owner state: w0-3 own layer1 col iu4+w; w4-7 layer2 col iu4+w-4 ----
    const int il = (w < 4) ? w : (w - 4);
    const int m  = lane;
    const int icol = iu4 + il;
    float bias[4];
    float c = 0.f;
    if (w < 8) {
        const float* bi = (w < 4) ? bih0 : bih1;
        const float* bh = (w < 4) ? bhh0 : bhh1;
        #pragma unroll
        for (int g = 0; g < 4; ++g)
            bias[g] = bi[icol + g * HDIM] + bh[icol + g * HDIM];
    }

    // ---- init: zero h^{(-1)} (frame 1) slices, publish ----
    if (w == 0) {
        st_cg8(ring1 + FRAME + oct4 * 512 + lane * 8 + coff, (uint2){0u, 0u});
        VM_DRAIN();
        if (lane == 0) bar_add(bar, slot);
    }
    if (w == 1) {
        st_cg8(ring2 + FRAME + oct4 * 512 + lane * 8 + coff, (uint2){0u, 0u});
        VM_DRAIN();
        if (lane == 0) bar_add(bar, slot);
    }

    for (int s = 0; s <= TDIM; ++s) {
        // ---- S1: wait for h1^{(s-1)} and h2^{(s-2)} (published step s-1) ----
        if (tid == 0) bar_wait(bar, (unsigned)(s + 1) * (2 * NBLK));
        __syncthreads();

        const f16* r1p = ring1 + (size_t)((s + 1) & 1) * FRAME;  // h1^{(s-1)}
        const f16* r2p = ring2 + (size_t)(s & 1) * FRAME;        // h2^{(s-2)}

        // ---- A1 fragments (16 loads in flight) + x loads ----
        f16x8 A1[4][4];
        #pragma unroll
        for (int j = 0; j < 4; ++j) {
            const int oct = (w * 4 + j) * 4 + quad;
            #pragma unroll
            for (int mt = 0; mt < 4; ++mt)
                A1[j][mt] = ld_cg(r1p + oct * 512 + (mt * 16 + am) * 8);
        }
        f16x8 ax[4];
        if (w < 4) {
            const int ts = (s < TDIM) ? s : (TDIM - 1);
            const f16* xb = xP + (size_t)ts * BDIM * KIN;
            const int kx = w * 32 + quad * 8;
            #pragma unroll
            for (int mt = 0; mt < 4; ++mt)
                ax[mt] = *(const f16x8*)(xb + (size_t)(mt * 16 + am) * KIN + kx);
        }
        VM_WAIT16(A1[0][0], A1[0][1], A1[0][2], A1[0][3],
                  A1[1][0], A1[1][1], A1[1][2], A1[1][3],
                  A1[2][0], A1[2][1], A1[2][2], A1[2][3],
                  A1[3][0], A1[3][1], A1[3][2], A1[3][3]);

        // ---- GEMV parts 1+2 (consume A1) ----
        f32x4 acc[4], acc2[4];
        #pragma unroll
        for (int mt = 0; mt < 4; ++mt) {
            acc[mt]  = (f32x4){0.f, 0.f, 0.f, 0.f};
            acc2[mt] = (f32x4){0.f, 0.f, 0.f, 0.f};
        }
        #pragma unroll
        for (int j = 0; j < 4; ++j)
            #pragma unroll
            for (int mt = 0; mt < 4; ++mt) {
                acc[mt]  = MFMA16(A1[j][mt], B1h[j], acc[mt]);
                acc2[mt] = MFMA16(A1[j][mt], B2i[j], acc2[mt]);
            }
        if (w < 4) {
            #pragma unroll
            for (int mt = 0; mt < 4; ++mt)
                acc[mt] = MFMA16(ax[mt], B1x, acc[mt]);
        }

        // ---- A2 fragments, GEMV part 3 ----
        f16x8 A2[4][4];
        #pragma unroll
        for (int j = 0; j < 4; ++j) {
            const int oct = (w * 4 + j) * 4 + quad;
            #pragma unroll
            for (int mt = 0; mt < 4; ++mt)
                A2[j][mt] = ld_cg(r2p + oct * 512 + (mt * 16 + am) * 8);
        }
        VM_WAIT16(A2[0][0], A2[0][1], A2[0][2], A2[0][3],
                  A2[1][0], A2[1][1], A2[1][2], A2[1][3],
                  A2[2][0], A2[2][1], A2[2][2], A2[2][3],
                  A2[3][0], A2[3][1], A2[3][2], A2[3][3]);
        #pragma unroll
        for (int j = 0; j < 4; ++j)
            #pragma unroll
            for (int mt = 0; mt < 4; ++mt)
                acc2[mt] = MFMA16(A2[j][mt], B2h[j], acc2[mt]);

        // ---- ONE reduction round: w<4 write, w>=4 fold (both buffers) ----
        const int p = w & 3;
        if (w < 4) {
            #pragma unroll
            for (int mt = 0; mt < 4; ++mt) {
                *(f32x4*)&red[(p * 4 + mt) * 324 + n * 20 + quad * 4] = acc[mt];
                *(f32x4*)&red[(16 + p * 4 + mt) * 324 + n * 20 + quad * 4] = acc2[mt];
            }
        }
        __syncthreads();   // S2
        if (w >= 4) {
            #pragma unroll
            for (int mt = 0; mt < 4; ++mt) {
                float* a1 = &red[(p * 4 + mt) * 324 + n * 20 + quad * 4];
                float* a2 = &red[(16 + p * 4 + mt) * 324 + n * 20 + quad * 4];
                f32x4 v1 = *(f32x4*)a1;
                f32x4 v2 = *(f32x4*)a2;
                *(f32x4*)a1 = v1 + acc[mt];
                *(f32x4*)a2 = v2 + acc2[mt];
            }
        }
        __syncthreads();   // S3

        // ---- parallel owners: w0-3 layer1, w4-7 layer2 ----
        if ((w < 4 && s < TDIM) || (w >= 4 && s >= 1)) {
            const int base = (w < 4) ? 0 : 16 * 324;
            const int mtm = m >> 4, qm = m & 15;
            float g4[4];
            #pragma unroll
            for (int g = 0; g < 4; ++g) {
                float sum = bias[g];
                #pragma unroll
                for (int pp = 0; pp < 4; ++pp)
                    sum += red[base + (pp * 4 + mtm) * 324 + (il * 4 + g) * 20 + qm];
                g4[g] = sum;
            }
            float ig = sigm(g4[0]), fg = sigm(g4[1]);
            float gg = tanhf(g4[2]), og = sigm(g4[3]);
            c = fg * c + ig * gg;
            float h = og * tanhf(c);
            if (w < 4) hbuf1[m * 4 + il] = (f16)h;
            else       hbuf2[m * 4 + il] = (f16)h;
        }
        __syncthreads();   // S4

        // ---- coalesced publications + arrivals ----
        if (w == 0) {
            if (s < TDIM) {
                uint2 v = *(const uint2*)&hbuf1[lane * 4];
                st_cg8(ring1 + (size_t)(s & 1) * FRAME + oct4 * 512 + lane * 8 + coff, v);
                VM_DRAIN();
            }
            if (lane == 0) bar_add(bar, slot);
        }
        if (w == 1) {
            if (s >= 1) {
                uint2 v = *(const uint2*)&hbuf2[lane * 4];
                st_cg8(ring2 + (size_t)((s + 1) & 1) * FRAME + oct4 * 512 + lane * 8 + coff, v);
                VM_DRAIN();
            }
            if (lane == 0) bar_add(bar, slot);
        }
    }
    // final h2^{(511)} is in ring2 frame 1
}

// ---------------------------------------------------------------------------
// out[b] = dot(h2[b, :], fc_w) + fc_b.  h2 in octet layout.
// ---------------------------------------------------------------------------
__global__ void fc_kernel(const f16* __restrict__ h2f,
                          const float* __restrict__ fcw,
                          const float* __restrict__ fcb,
                          float* __restrict__ out) {
    __shared__ float red[256];
    const int tid = threadIdx.x;
    const int b = tid >> 2, q = tid & 3;
    float s = 0.f;
    for (int oct = q * 32; oct < (q + 1) * 32; ++oct) {
        f16x8 v = *(const f16x8*)(h2f + oct * 512 + b * 8);
        #pragma unroll
        for (int j = 0; j < 8; ++j)
            s = fmaf((float)v[j], fcw[oct * 8 + j], s);
    }
    red[tid] = s;
    __syncthreads();
    if (q == 0)
        out[b] = red[tid] + red[tid + 1] + red[tid + 2] + red[tid + 3] + fcb[0];
}

// ---------------------------------------------------------------------------
extern "C" void kernel_launch(void* const* d_in, const int* in_sizes, int n_in,
                              void* d_out, int out_size, void* d_ws, size_t ws_size,
                              hipStream_t stream) {
    const float* x    = (const float*)d_in[0];
    const float* Wih0 = (const float*)d_in[1];
    const float* Whh0 = (const float*)d_in[2];
    const float* bih0 = (const float*)d_in[3];
    const float* bhh0 = (const float*)d_in[4];
    const float* Wih1 = (const float*)d_in[5];
    const float* Whh1 = (const float*)d_in[6];
    const float* bih1 = (const float*)d_in[7];
    const float* bhh1 = (const float*)d_in[8];
    const float* fcw  = (const float*)d_in[9];
    const float* fcb  = (const float*)d_in[10];
    float* out = (float*)d_out;

    // workspace (halfs): xP | Wc0 | Wh0 | Wc1 | Wh1 | ring1 | ring2 | barrier
    f16* xPd   = (f16*)d_ws;
    f16* Wc0   = xPd + (size_t)TDIM * BDIM * KIN;
    f16* Wh0   = Wc0 + (size_t)4 * HDIM * KIN;
    f16* Wc1   = Wh0 + (size_t)4 * HDIM * HDIM;
    f16* Wh1   = Wc1 + (size_t)4 * HDIM * HDIM;
    f16* ring1 = Wh1 + (size_t)4 * HDIM * HDIM;
    f16* ring2 = ring1 + 2 * FRAME;
    unsigned* bar = (unsigned*)(ring2 + 2 * FRAME);

    hipMemsetAsync(bar, 0, 4096, stream);
    {
        int n2 = 4 * HDIM * KIN / 2;
        cvt_w<<<dim3((n2 + 255) / 256), dim3(256), 0, stream>>>(Wih0, Wc0, n2);
        n2 = 4 * HDIM * HDIM / 2;
        cvt_w<<<dim3((n2 + 255) / 256), dim3(256), 0, stream>>>(Whh0, Wh0, n2);
        cvt_w<<<dim3((n2 + 255) / 256), dim3(256), 0, stream>>>(Whh1, Wh1, n2);
        cvt_w<<<dim3((n2 + 255) / 256), dim3(256), 0, stream>>>(Wih1, Wc1, n2);
    }
    {
        int np = TDIM * BDIM * (KIN / 2);
        cvt_x<<<dim3((np + 255) / 256), dim3(256), 0, stream>>>(x, xPd);
    }

    void* args[12];
    args[0]  = (void*)&xPd;
    args[1]  = (void*)&Wc0;
    args[2]  = (void*)&Wh0;
    args[3]  = (void*)&bih0;
    args[4]  = (void*)&bhh0;
    args[5]  = (void*)&Wc1;
    args[6]  = (void*)&Wh1;
    args[7]  = (void*)&bih1;
    args[8]  = (void*)&bhh1;
    args[9]  = (void*)&ring1;
    args[10] = (void*)&ring2;
    args[11] = (void*)&bar;
    hipLaunchCooperativeKernel(reinterpret_cast<void*>(lstm_fused), dim3(NBLK), dim3(NTHR),
                               args, 0, stream);

    fc_kernel<<<dim3(1), dim3(256), 0, stream>>>(ring2 + FRAME, fcw, fcb, out);
}

// Round 11
// 3912.432 us; speedup vs baseline: 1.0135x; 1.0135x over previous
//
#include <hip/hip_runtime.h>
#include <math.h>

#define HDIM 1024
#define BDIM 64
#define TDIM 512
#define KIN  128
#define NBLK 256            // 128 layer-1 blocks + 128 layer-2 blocks
#define NTHR 1024           // 16 waves
#define FRAME (HDIM * BDIM) // halfs per ring frame (4-deep rings)
#define LHALF 128           // blocks per layer

typedef _Float16 f16;
typedef __attribute__((ext_vector_type(2))) _Float16 f16x2;
typedef __attribute__((ext_vector_type(8))) _Float16 f16x8;
typedef __attribute__((ext_vector_type(4))) float f32x4;
typedef __attribute__((ext_vector_type(4))) unsigned u32x4;

#define MFMA16(a, b, c) __builtin_amdgcn_mfma_f32_16x16x32_f16((a), (b), (c), 0, 0, 0)

__device__ __forceinline__ float sigm(float x) { return 1.0f / (1.0f + expf(-x)); }

// ---------------------------------------------------------------------------
// Octet ring layout (halfs): idx(k, m) = (k>>3)*512 + m*8 + (k&7).
// A-frag load = one dwordx4/lane; block owns exactly one octet (8 cols) ->
// h-publish = one contiguous 1 KB dwordx4 wave-store.
// All ring I/O sc0sc1 (L3-coherent, fence-free).
// ---------------------------------------------------------------------------
__device__ __forceinline__ f16x8 ld_cg(const f16* p) {
    f16x8 r;
    asm volatile("global_load_dwordx4 %0, %1, off sc0 sc1"
                 : "=v"(r) : "v"(p) : "memory");
    return r;
}
#define VM_WAIT8(r0, r1, r2, r3, r4, r5, r6, r7)                         \
    asm volatile("s_waitcnt vmcnt(0)"                                    \
                 : "+v"(r0), "+v"(r1), "+v"(r2), "+v"(r3),               \
                   "+v"(r4), "+v"(r5), "+v"(r6), "+v"(r7))

__device__ __forceinline__ void st_cg16(f16* p, u32x4 v) {
    asm volatile("global_store_dwordx4 %0, %1, off sc0 sc1"
                 :: "v"(p), "v"(v) : "memory");
}
#define VM_DRAIN() asm volatile("s_waitcnt vmcnt(0)" ::: "memory")

// ---------------------------------------------------------------------------
// Flat-8 fence-free barrier: monotonic counters on 8 parallel 128B lines;
// wait = poll sum >= target. 128 arrivals per step per barrier.
// ---------------------------------------------------------------------------
__device__ __forceinline__ void bar_add(unsigned* base, int slot) {
    __hip_atomic_fetch_add(base + slot * 32, 1u, __ATOMIC_RELAXED,
                           __HIP_MEMORY_SCOPE_AGENT);
}
__device__ __forceinline__ void bar_wait(unsigned* base, unsigned target) {
    for (;;) {
        unsigned sum = 0;
        #pragma unroll
        for (int i = 0; i < 8; ++i)
            sum += __hip_atomic_load(base + i * 32, __ATOMIC_RELAXED,
                                     __HIP_MEMORY_SCOPE_AGENT);
        if (sum >= target) break;
        __builtin_amdgcn_s_sleep(1);
    }
}

// ---------------------------------------------------------------------------
__global__ void cvt_w(const float* __restrict__ src, f16* __restrict__ dst, int n2) {
    int i = blockIdx.x * blockDim.x + threadIdx.x;
    if (i < n2) {
        float2 a = ((const float2*)src)[i];
        f16x2 o = {(f16)a.x, (f16)a.y};
        ((f16x2*)dst)[i] = o;
    }
}

// x[b][t][k] fp32 -> xP[t][b][k] fp16
__global__ void cvt_x(const float* __restrict__ x, f16* __restrict__ xP) {
    int P = blockIdx.x * blockDim.x + threadIdx.x;    // pair index
    if (P >= TDIM * BDIM * (KIN / 2)) return;
    int kp = P & 63;
    int b  = (P >> 6) & 63;
    int t  = P >> 12;
    float2 v = ((const float2*)x)[((size_t)b * TDIM + t) * (KIN / 2) + kp];
    f16x2 o = {(f16)v.x, (f16)v.y};
    ((f16x2*)xP)[((size_t)t * BDIM + b) * (KIN / 2) + kp] = o;
}

// ---------------------------------------------------------------------------
// Fused 2-layer LSTM, spatially split: blocks 0..127 run layer 1's
// recurrence, blocks 128..255 run layer 2's — concurrently on disjoint CUs.
// Each block: 16 waves, owns 8 hidden cols (1 octet, 2 MFMA n-tiles). Wave w
// covers K-slice [w*64,(w+1)*64). Per step: barrier wait(s) -> A loads ->
// MFMA -> 4-deep LDS fold (write w0-3; add w4-7, w8-11, w12-15) -> owner
// waves 0..7 (col=w, lane=batch, c in regs) -> hbuf -> wave 8 publishes one
// 1KB dwordx4 store -> arrive. 4-deep rings give slack-3 cross-chain
// throttle so the chains decouple.
// ---------------------------------------------------------------------------
__global__ void __launch_bounds__(NTHR, 4) lstm_fused(
    const f16* __restrict__ xP,
    const f16* __restrict__ Wc0, const f16* __restrict__ Wh0,
    const float* __restrict__ bih0, const float* __restrict__ bhh0,
    const f16* __restrict__ Wc1, const f16* __restrict__ Wh1,
    const float* __restrict__ bih1, const float* __restrict__ bhh1,
    f16* ring1, f16* ring2, unsigned* barA, unsigned* barB) {

    // red group g(nt,p,mt) = ((nt*4+p)*4+mt)*324 + n*20 + quad*4 : 41.5 KB
    __shared__ float red[32 * 324 + 16];
    __shared__ __align__(16) f16 hbuf[BDIM * 8];

    const int tid  = threadIdx.x;
    const int lane = tid & 63;
    const int w    = __builtin_amdgcn_readfirstlane(tid >> 6);   // 0..15
    const int bid  = (int)blockIdx.x;
    const int lay2 = bid >> 7;                 // 0 = layer1, 1 = layer2
    const int oct  = __builtin_amdgcn_readfirstlane(bid & 127);
    const int iu8  = oct * 8;
    const int slot = bid & 7;

    const int n    = lane & 15;
    const int quad = lane >> 4;
    const int am   = lane & 15;
    const int m    = lane;

    // weight rows for the two n-tiles
    int wr0 = iu8 + (n >> 2) + (n & 3) * HDIM;
    int wr1 = wr0 + 4;

    // ---- owner state: wave w<8 owns col il = w ----
    const int il = w & 7;
    const int icol = iu8 + il;
    float bias[4];
    float c = 0.f;
    {
        const float* bi = lay2 ? bih1 : bih0;
        const float* bh = lay2 ? bhh1 : bhh0;
        #pragma unroll
        for (int g = 0; g < 4; ++g)
            bias[g] = bi[icol + g * HDIM] + bh[icol + g * HDIM];
    }

    const int p = w & 3;

    if (!lay2) {
        // =================== LAYER 1 blocks ===================
        f16x8 B1h[2][2], B1x[2];
        #pragma unroll
        for (int j = 0; j < 2; ++j) {
            const int ks = (2 * w + j) * 32 + quad * 8;
            B1h[j][0] = *(const f16x8*)(Wh0 + (size_t)wr0 * HDIM + ks);
            B1h[j][1] = *(const f16x8*)(Wh0 + (size_t)wr1 * HDIM + ks);
        }
        if (w < 4) {
            const int kx = w * 32 + quad * 8;
            B1x[0] = *(const f16x8*)(Wc0 + (size_t)wr0 * KIN + kx);
            B1x[1] = *(const f16x8*)(Wc0 + (size_t)wr1 * KIN + kx);
        }
        // init h1^{(-1)} = 0 in frame 3
        if (w == 8) {
            st_cg16(ring1 + 3 * (size_t)FRAME + oct * 512 + lane * 8,
                    (u32x4){0u, 0u, 0u, 0u});
            VM_DRAIN();
            if (lane == 0) bar_add(barA, slot);
        }

        for (int t = 0; t < TDIM; ++t) {
            if (tid == 0)  bar_wait(barA, (unsigned)(t + 1) * LHALF);
            if (tid == 64 && t >= 4) bar_wait(barB, (unsigned)(t - 2) * LHALF);
            __syncthreads();

            const f16* r1p = ring1 + (size_t)((t + 3) & 3) * FRAME; // h1^{(t-1)}
            f16x8 A1[2][4];
            #pragma unroll
            for (int j = 0; j < 2; ++j) {
                const int ok = (2 * w + j) * 4 + quad;
                #pragma unroll
                for (int mt = 0; mt < 4; ++mt)
                    A1[j][mt] = ld_cg(r1p + ok * 512 + (mt * 16 + am) * 8);
            }
            f16x8 ax[4];
            if (w < 4) {
                const f16* xb = xP + (size_t)t * BDIM * KIN;
                const int kx = w * 32 + quad * 8;
                #pragma unroll
                for (int mt = 0; mt < 4; ++mt)
                    ax[mt] = *(const f16x8*)(xb + (size_t)(mt * 16 + am) * KIN + kx);
            }
            VM_WAIT8(A1[0][0], A1[0][1], A1[0][2], A1[0][3],
                     A1[1][0], A1[1][1], A1[1][2], A1[1][3]);

            f32x4 acc[2][4];
            #pragma unroll
            for (int nt = 0; nt < 2; ++nt)
                #pragma unroll
                for (int mt = 0; mt < 4; ++mt)
                    acc[nt][mt] = (f32x4){0.f, 0.f, 0.f, 0.f};
            #pragma unroll
            for (int j = 0; j < 2; ++j)
                #pragma unroll
                for (int nt = 0; nt < 2; ++nt)
                    #pragma unroll
                    for (int mt = 0; mt < 4; ++mt)
                        acc[nt][mt] = MFMA16(A1[j][mt], B1h[j][nt], acc[nt][mt]);
            if (w < 4) {
                #pragma unroll
                for (int nt = 0; nt < 2; ++nt)
                    #pragma unroll
                    for (int mt = 0; mt < 4; ++mt)
                        acc[nt][mt] = MFMA16(ax[mt], B1x[nt], acc[nt][mt]);
            }

            // ---- 4-deep fold: w0-3 write, then 3 add rounds ----
            if (w < 4) {
                #pragma unroll
                for (int nt = 0; nt < 2; ++nt)
                    #pragma unroll
                    for (int mt = 0; mt < 4; ++mt)
                        *(f32x4*)&red[((nt * 4 + p) * 4 + mt) * 324 + n * 20 + quad * 4] = acc[nt][mt];
            }
            __syncthreads();
            if (w >= 4 && w < 8) {
                #pragma unroll
                for (int nt = 0; nt < 2; ++nt)
                    #pragma unroll
                    for (int mt = 0; mt < 4; ++mt) {
                        float* a = &red[((nt * 4 + p) * 4 + mt) * 324 + n * 20 + quad * 4];
                        *(f32x4*)a = *(f32x4*)a + acc[nt][mt];
                    }
            }
            __syncthreads();
            if (w >= 8 && w < 12) {
                #pragma unroll
                for (int nt = 0; nt < 2; ++nt)
                    #pragma unroll
                    for (int mt = 0; mt < 4; ++mt) {
                        float* a = &red[((nt * 4 + p) * 4 + mt) * 324 + n * 20 + quad * 4];
                        *(f32x4*)a = *(f32x4*)a + acc[nt][mt];
                    }
            }
            __syncthreads();
            if (w >= 12) {
                #pragma unroll
                for (int nt = 0; nt < 2; ++nt)
                    #pragma unroll
                    for (int mt = 0; mt < 4; ++mt) {
                        float* a = &red[((nt * 4 + p) * 4 + mt) * 324 + n * 20 + quad * 4];
                        *(f32x4*)a = *(f32x4*)a + acc[nt][mt];
                    }
            }
            __syncthreads();

            // ---- owners (w0-7): gates -> c1 -> h1 into hbuf ----
            if (w < 8) {
                const int ntl = il >> 2, cl = il & 3;
                const int mtm = m >> 4, qm = m & 15;
                float g4[4];
                #pragma unroll
                for (int g = 0; g < 4; ++g) {
                    float sum = bias[g];
                    #pragma unroll
                    for (int pp = 0; pp < 4; ++pp)
                        sum += red[((ntl * 4 + pp) * 4 + mtm) * 324 + (cl * 4 + g) * 20 + qm];
                    g4[g] = sum;
                }
                float ig = sigm(g4[0]), fg = sigm(g4[1]);
                float gg = tanhf(g4[2]), og = sigm(g4[3]);
                c = fg * c + ig * gg;
                hbuf[m * 8 + il] = (f16)(og * tanhf(c));
            }
            __syncthreads();

            if (w == 8) {
                u32x4 v = *(const u32x4*)&hbuf[lane * 8];
                st_cg16(ring1 + (size_t)(t & 3) * FRAME + oct * 512 + lane * 8, v);
                VM_DRAIN();
                if (lane == 0) bar_add(barA, slot);
            }
        }
    } else {
        // =================== LAYER 2 blocks ===================
        f16x8 B2i[2][2], B2h[2][2];
        #pragma unroll
        for (int j = 0; j < 2; ++j) {
            const int ks = (2 * w + j) * 32 + quad * 8;
            B2i[j][0] = *(const f16x8*)(Wc1 + (size_t)wr0 * HDIM + ks);
            B2i[j][1] = *(const f16x8*)(Wc1 + (size_t)wr1 * HDIM + ks);
            B2h[j][0] = *(const f16x8*)(Wh1 + (size_t)wr0 * HDIM + ks);
            B2h[j][1] = *(const f16x8*)(Wh1 + (size_t)wr1 * HDIM + ks);
        }
        // init h2^{(-1)} = 0 in frame 3
        if (w == 8) {
            st_cg16(ring2 + 3 * (size_t)FRAME + oct * 512 + lane * 8,
                    (u32x4){0u, 0u, 0u, 0u});
            VM_DRAIN();
            if (lane == 0) bar_add(barB, slot);
        }

        for (int u = 0; u < TDIM; ++u) {
            if (tid == 0)  bar_wait(barB, (unsigned)(u + 1) * LHALF);
            if (tid == 64) bar_wait(barA, (unsigned)(u + 2) * LHALF);
            __syncthreads();

            const f16* r2p = ring2 + (size_t)((u + 3) & 3) * FRAME; // h2^{(u-1)}
            const f16* r1p = ring1 + (size_t)(u & 3) * FRAME;       // h1^{(u)}

            f32x4 acc2[2][4];
            #pragma unroll
            for (int nt = 0; nt < 2; ++nt)
                #pragma unroll
                for (int mt = 0; mt < 4; ++mt)
                    acc2[nt][mt] = (f32x4){0.f, 0.f, 0.f, 0.f};

            {   // own recurrence first: A2 = h2^{(u-1)}
                f16x8 A[2][4];
                #pragma unroll
                for (int j = 0; j < 2; ++j) {
                    const int ok = (2 * w + j) * 4 + quad;
                    #pragma unroll
                    for (int mt = 0; mt < 4; ++mt)
                        A[j][mt] = ld_cg(r2p + ok * 512 + (mt * 16 + am) * 8);
                }
                VM_WAIT8(A[0][0], A[0][1], A[0][2], A[0][3],
                         A[1][0], A[1][1], A[1][2], A[1][3]);
                #pragma unroll
                for (int j = 0; j < 2; ++j)
                    #pragma unroll
                    for (int nt = 0; nt < 2; ++nt)
                        #pragma unroll
                        for (int mt = 0; mt < 4; ++mt)
                            acc2[nt][mt] = MFMA16(A[j][mt], B2h[j][nt], acc2[nt][mt]);
            }
            {   // then A1 = h1^{(u)}
                f16x8 A[2][4];
                #pragma unroll
                for (int j = 0; j < 2; ++j) {
                    const int ok = (2 * w + j) * 4 + quad;
                    #pragma unroll
                    for (int mt = 0; mt < 4; ++mt)
                        A[j][mt] = ld_cg(r1p + ok * 512 + (mt * 16 + am) * 8);
                }
                VM_WAIT8(A[0][0], A[0][1], A[0][2], A[0][3],
                         A[1][0], A[1][1], A[1][2], A[1][3]);
                #pragma unroll
                for (int j = 0; j < 2; ++j)
                    #pragma unroll
                    for (int nt = 0; nt < 2; ++nt)
                        #pragma unroll
                        for (int mt = 0; mt < 4; ++mt)
                            acc2[nt][mt] = MFMA16(A[j][mt], B2i[j][nt], acc2[nt][mt]);
            }

            // ---- 4-deep fold ----
            if (w < 4) {
                #pragma unroll
                for (int nt = 0; nt < 2; ++nt)
                    #pragma unroll
                    for (int mt = 0; mt < 4; ++mt)
                        *(f32x4*)&red[((nt * 4 + p) * 4 + mt) * 324 + n * 20 + quad * 4] = acc2[nt][mt];
            }
            __syncthreads();
            if (w >= 4 && w < 8) {
                #pragma unroll
                for (int nt = 0; nt < 2; ++nt)
                    #pragma unroll
                    for (int mt = 0; mt < 4; ++mt) {
                        float* a = &red[((nt * 4 + p) * 4 + mt) * 324 + n * 20 + quad * 4];
                        *(f32x4*)a = *(f32x4*)a + acc2[nt][mt];
                    }
            }
            __syncthreads();
            if (w >= 8 && w < 12) {
                #pragma unroll
                for (int nt = 0; nt < 2; ++nt)
                    #pragma unroll
                    for (int mt = 0; mt < 4; ++mt) {
                        float* a = &red[((nt * 4 + p) * 4 + mt) * 324 + n * 20 + quad * 4];
                        *(f32x4*)a = *(f32x4*)a + acc2[nt][mt];
                    }
            }
            __syncthreads();
            if (w >= 12) {
                #pragma unroll
                for (int nt = 0; nt < 2; ++nt)
                    #pragma unroll
                    for (int mt = 0; mt < 4; ++mt) {
                        float* a = &red[((nt * 4 + p) * 4 + mt) * 324 + n * 20 + quad * 4];
                        *(f32x4*)a = *(f32x4*)a + acc2[nt][mt];
                    }
            }
            __syncthreads();

            // ---- owners (w0-7): gates -> c2 -> h2 into hbuf ----
            if (w < 8) {
                const int ntl = il >> 2, cl = il & 3;
                const int mtm = m >> 4, qm = m & 15;
                float g4[4];
                #pragma unroll
                for (int g = 0; g < 4; ++g) {
                    float sum = bias[g];
                    #pragma unroll
                    for (int pp = 0; pp < 4; ++pp)
                        sum += red[((ntl * 4 + pp) * 4 + mtm) * 324 + (cl * 4 + g) * 20 + qm];
                    g4[g] = sum;
                }
                float ig = sigm(g4[0]), fg = sigm(g4[1]);
                float gg = tanhf(g4[2]), og = sigm(g4[3]);
                c = fg * c + ig * gg;
                hbuf[m * 8 + il] = (f16)(og * tanhf(c));
            }
            __syncthreads();

            if (w == 8) {
                u32x4 v = *(const u32x4*)&hbuf[lane * 8];
                st_cg16(ring2 + (size_t)(u & 3) * FRAME + oct * 512 + lane * 8, v);
                VM_DRAIN();
                if (lane == 0) bar_add(barB, slot);
            }
        }
    }
    // final h2^{(511)} is in ring2 frame 3 (511 & 3)
}

// ---------------------------------------------------------------------------
// out[b] = dot(h2[b, :], fc_w) + fc_b.  h2 in octet layout.
// ---------------------------------------------------------------------------
__global__ void fc_kernel(const f16* __restrict__ h2f,
                          const float* __restrict__ fcw,
                          const float* __restrict__ fcb,
                          float* __restrict__ out) {
    __shared__ float red[256];
    const int tid = threadIdx.x;
    const int b = tid >> 2, q = tid & 3;
    float s = 0.f;
    for (int oct = q * 32; oct < (q + 1) * 32; ++oct) {
        f16x8 v = *(const f16x8*)(h2f + oct * 512 + b * 8);
        #pragma unroll
        for (int j = 0; j < 8; ++j)
            s = fmaf((float)v[j], fcw[oct * 8 + j], s);
    }
    red[tid] = s;
    __syncthreads();
    if (q == 0)
        out[b] = red[tid] + red[tid + 1] + red[tid + 2] + red[tid + 3] + fcb[0];
}

// ---------------------------------------------------------------------------
extern "C" void kernel_launch(void* const* d_in, const int* in_sizes, int n_in,
                              void* d_out, int out_size, void* d_ws, size_t ws_size,
                              hipStream_t stream) {
    const float* x    = (const float*)d_in[0];
    const float* Wih0 = (const float*)d_in[1];
    const float* Whh0 = (const float*)d_in[2];
    const float* bih0 = (const float*)d_in[3];
    const float* bhh0 = (const float*)d_in[4];
    const float* Wih1 = (const float*)d_in[5];
    const float* Whh1 = (const float*)d_in[6];
    const float* bih1 = (const float*)d_in[7];
    const float* bhh1 = (const float*)d_in[8];
    const float* fcw  = (const float*)d_in[9];
    const float* fcb  = (const float*)d_in[10];
    float* out = (float*)d_out;

    // workspace (halfs): xP | Wc0 | Wh0 | Wc1 | Wh1 | ring1[4F] | ring2[4F] | bars
    f16* xPd   = (f16*)d_ws;
    f16* Wc0   = xPd + (size_t)TDIM * BDIM * KIN;
    f16* Wh0   = Wc0 + (size_t)4 * HDIM * KIN;
    f16* Wc1   = Wh0 + (size_t)4 * HDIM * HDIM;
    f16* Wh1   = Wc1 + (size_t)4 * HDIM * HDIM;
    f16* ring1 = Wh1 + (size_t)4 * HDIM * HDIM;
    f16* ring2 = ring1 + 4 * (size_t)FRAME;
    unsigned* barA = (unsigned*)(ring2 + 4 * (size_t)FRAME);
    unsigned* barB = barA + 1024;

    hipMemsetAsync(barA, 0, 8192, stream);
    {
        int n2 = 4 * HDIM * KIN / 2;
        cvt_w<<<dim3((n2 + 255) / 256), dim3(256), 0, stream>>>(Wih0, Wc0, n2);
        n2 = 4 * HDIM * HDIM / 2;
        cvt_w<<<dim3((n2 + 255) / 256), dim3(256), 0, stream>>>(Whh0, Wh0, n2);
        cvt_w<<<dim3((n2 + 255) / 256), dim3(256), 0, stream>>>(Whh1, Wh1, n2);
        cvt_w<<<dim3((n2 + 255) / 256), dim3(256), 0, stream>>>(Wih1, Wc1, n2);
    }
    {
        int np = TDIM * BDIM * (KIN / 2);
        cvt_x<<<dim3((np + 255) / 256), dim3(256), 0, stream>>>(x, xPd);
    }

    void* args[13];
    args[0]  = (void*)&xPd;
    args[1]  = (void*)&Wc0;
    args[2]  = (void*)&Wh0;
    args[3]  = (void*)&bih0;
    args[4]  = (void*)&bhh0;
    args[5]  = (void*)&Wc1;
    args[6]  = (void*)&Wh1;
    args[7]  = (void*)&bih1;
    args[8]  = (void*)&bhh1;
    args[9]  = (void*)&ring1;
    args[10] = (void*)&ring2;
    args[11] = (void*)&barA;
    args[12] = (void*)&barB;
    hipLaunchCooperativeKernel(reinterpret_cast<void*>(lstm_fused), dim3(NBLK), dim3(NTHR),
                               args, 0, stream);

    fc_kernel<<<dim3(1), dim3(256), 0, stream>>>(ring2 + 3 * (size_t)FRAME, fcw, fcb, out);
}